// Round 3
// baseline (68.917 us; speedup 1.0000x reference)
//
#include <hip/hip_runtime.h>
#include <hip/hip_bf16.h>

// kernel[i,j] = | prod_k cos((x[i,k]-y[j,k])/2) |
//             = | prod_k ( cos(x/2)cos(y/2) + sin(x/2)sin(y/2) ) |
//
// Dtypes (established r0-r2):
//   inputs : float32 storage (reading as bf16 gave NaN -> r1)
//   output : float32 storage (writing bf16 gave error == positional-mismatch
//            pattern with max ~max(ref) -> r2; harness reads d_out as f32)
//
// Tile: 128 rows x 64 cols per 256-thread block; each thread computes 8x4
// outputs (rows split as two quads r0,r0+64 so LDS reads are ds_read_b128).
// sin/cos staged in LDS in [k][row] layout (padded +4 keeps float4 16B
// alignment and breaks the power-of-2 stride).

constexpr int D  = 16;    // wires
constexpr int BR = 128;   // rows per block
constexpr int BC = 64;    // cols per block
constexpr int BRP = BR + 4;
constexpr int BCP = BC + 4;
constexpr int NT = 256;   // threads per block (4 waves)

__global__ __launch_bounds__(NT)
void qkern(const float* __restrict__ x,
           const float* __restrict__ y,
           float* __restrict__ out,
           int n, int m) {
    __shared__ float cx[D][BRP];
    __shared__ float sx[D][BRP];
    __shared__ float cy[D][BCP];
    __shared__ float sy[D][BCP];

    const int row0 = blockIdx.x * BR;
    const int col0 = blockIdx.y * BC;
    const int tid  = threadIdx.x;

    // Stage sin/cos of x/2 for this block's 128 rows (2048 values, 8/thread).
    for (int i = tid; i < BR * D; i += NT) {
        float v = x[(size_t)row0 * D + i];
        int r = i >> 4, k = i & 15;
        float s, c;
        __sincosf(0.5f * v, &s, &c);
        cx[k][r] = c;
        sx[k][r] = s;
    }
    // Stage sin/cos of y/2 for this block's 64 cols (1024 values, 4/thread).
    for (int i = tid; i < BC * D; i += NT) {
        float v = y[(size_t)col0 * D + i];
        int r = i >> 4, k = i & 15;
        float s, c;
        __sincosf(0.5f * v, &s, &c);
        cy[k][r] = c;
        sy[k][r] = s;
    }
    __syncthreads();

    const int rg = tid >> 4;   // 0..15 -> row quads at rg*4 and rg*4+64
    const int cg = tid & 15;   // 0..15 -> col quad at cg*4
    const int r0 = rg * 4;
    const int c0 = cg * 4;

    float p[2][4][4];
#pragma unroll
    for (int h = 0; h < 2; ++h)
#pragma unroll
        for (int a = 0; a < 4; ++a)
#pragma unroll
            for (int b = 0; b < 4; ++b)
                p[h][a][b] = 1.0f;

#pragma unroll
    for (int k = 0; k < D; ++k) {
        // b128 LDS loads; addresses 16B-aligned (BRP,BCP multiples of 4).
        float4 cxa = *(const float4*)&cx[k][r0];
        float4 sxa = *(const float4*)&sx[k][r0];
        float4 cxb = *(const float4*)&cx[k][r0 + 64];
        float4 sxb = *(const float4*)&sx[k][r0 + 64];
        float4 cyv = *(const float4*)&cy[k][c0];
        float4 syv = *(const float4*)&sy[k][c0];

        const float cxr[8] = {cxa.x, cxa.y, cxa.z, cxa.w,
                              cxb.x, cxb.y, cxb.z, cxb.w};
        const float sxr[8] = {sxa.x, sxa.y, sxa.z, sxa.w,
                              sxb.x, sxb.y, sxb.z, sxb.w};
        const float cyr[4] = {cyv.x, cyv.y, cyv.z, cyv.w};
        const float syr[4] = {syv.x, syv.y, syv.z, syv.w};

#pragma unroll
        for (int a = 0; a < 8; ++a)
#pragma unroll
            for (int b = 0; b < 4; ++b) {
                float t = fmaf(sxr[a], syr[b], cxr[a] * cyr[b]);
                p[a >> 2][a & 3][b] *= t;
            }
    }

    // Store 8 rows x 4 cols as float4 (16B per row-store, 16B-aligned:
    // col0+c0 is a multiple of 4 floats).
#pragma unroll
    for (int h = 0; h < 2; ++h)
#pragma unroll
        for (int a = 0; a < 4; ++a) {
            int row = row0 + r0 + h * 64 + a;
            float4 v;
            v.x = fabsf(p[h][a][0]);
            v.y = fabsf(p[h][a][1]);
            v.z = fabsf(p[h][a][2]);
            v.w = fabsf(p[h][a][3]);
            *(float4*)&out[(size_t)row * m + col0 + c0] = v;
        }
}

extern "C" void kernel_launch(void* const* d_in, const int* in_sizes, int n_in,
                              void* d_out, int out_size, void* d_ws, size_t ws_size,
                              hipStream_t stream) {
    const float* x = (const float*)d_in[0];
    const float* y = (const float*)d_in[1];
    float* out = (float*)d_out;
    const int n = in_sizes[0] / D;  // 2048
    const int m = in_sizes[1] / D;  // 2048
    dim3 grid(n / BR, m / BC);      // 16 x 32 = 512 blocks -> 2 blocks/CU
    qkern<<<grid, NT, 0, stream>>>(x, y, out, n, m);
}

// Round 4
// 66.315 us; speedup vs baseline: 1.0392x; 1.0392x over previous
//
#include <hip/hip_runtime.h>
#include <hip/hip_bf16.h>

// kernel[i,j] = | prod_k cos((x[i,k]-y[j,k])/2) |
//             = | prod_k ( cos(x/2)cos(y/2) + sin(x/2)sin(y/2) ) |
//
// Dtypes (established r0-r3): inputs float32, output float32 (passed r3,
// absmax 1.95e-3 vs threshold 1.56e-2).
//
// r4 changes vs r3 (passed @ dur_us 68.9, qkern's own dispatch < 41 us):
//  - float2 packed math in the inner product -> v_pk_mul_f32/v_pk_fma_f32
//    (halves VALU issue: 96 -> 48 ops per k per thread)
//  - no dynamically-indexed local arrays anywhere (spill-proofing; r3 had
//    cxr[8]/p[2][4][4] which *should* promote post-unroll, but we can't see
//    qkern's FETCH/WRITE row to rule out scratch traffic)
//
// Tile: 128 rows x 64 cols per 256-thread block; 8x4 outputs/thread (rows as
// two quads r0, r0+64 so all LDS reads are ds_read_b128). LDS in [k][row]
// layout, padded +4 (16B alignment kept; power-of-2 stride broken).
// Structural floors @ 2.4 GHz: LDS pipe 768 b128/CU x 12cyc = 3.84 us,
// VALU (pk) 1.28 us, HBM write 16.8 MB = 2.7 us.

constexpr int D  = 16;    // wires
constexpr int BR = 128;   // rows per block
constexpr int BC = 64;    // cols per block
constexpr int BRP = BR + 4;
constexpr int BCP = BC + 4;
constexpr int NT = 256;   // threads per block (4 waves)

__global__ __launch_bounds__(NT)
void qkern(const float* __restrict__ x,
           const float* __restrict__ y,
           float* __restrict__ out,
           int n, int m) {
    __shared__ float cx[D][BRP];
    __shared__ float sx[D][BRP];
    __shared__ float cy[D][BCP];
    __shared__ float sy[D][BCP];

    const int row0 = blockIdx.x * BR;
    const int col0 = blockIdx.y * BC;
    const int tid  = threadIdx.x;

    // Stage sin/cos(x/2) for 128 rows (2048 vals, 8/thread).
    for (int i = tid; i < BR * D; i += NT) {
        float v = x[(size_t)row0 * D + i];
        int r = i >> 4, k = i & 15;
        float s, c;
        __sincosf(0.5f * v, &s, &c);
        cx[k][r] = c;
        sx[k][r] = s;
    }
    // Stage sin/cos(y/2) for 64 cols (1024 vals, 4/thread).
    for (int i = tid; i < BC * D; i += NT) {
        float v = y[(size_t)col0 * D + i];
        int r = i >> 4, k = i & 15;
        float s, c;
        __sincosf(0.5f * v, &s, &c);
        cy[k][r] = c;
        sy[k][r] = s;
    }
    __syncthreads();

    const int rg = tid >> 4;   // row quads at rg*4 and rg*4+64
    const int cg = tid & 15;   // col quad at cg*4
    const int r0 = rg * 4;
    const int c0 = cg * 4;

    // p0[a] = cols {0,1}, p1[a] = cols {2,3} for row a (a<4: r0+a, a>=4: r0+64+a-4)
    float2 p0[8], p1[8];
#pragma unroll
    for (int a = 0; a < 8; ++a) {
        p0[a] = make_float2(1.0f, 1.0f);
        p1[a] = make_float2(1.0f, 1.0f);
    }

#pragma unroll
    for (int k = 0; k < D; ++k) {
        // 6 ds_read_b128 per k (16B-aligned: BRP/BCP multiples of 4).
        const float4 cxa = *(const float4*)&cx[k][r0];
        const float4 sxa = *(const float4*)&sx[k][r0];
        const float4 cxb = *(const float4*)&cx[k][r0 + 64];
        const float4 sxb = *(const float4*)&sx[k][r0 + 64];
        const float4 cyv = *(const float4*)&cy[k][c0];
        const float4 syv = *(const float4*)&sy[k][c0];

        const float2 cy01 = make_float2(cyv.x, cyv.y);
        const float2 cy23 = make_float2(cyv.z, cyv.w);
        const float2 sy01 = make_float2(syv.x, syv.y);
        const float2 sy23 = make_float2(syv.z, syv.w);

        // t = c_x*c_y + s_x*s_y, p *= t  -- as <2 x float> packed ops.
#define QROW(idx, CR, SR)                                                   \
        {                                                                   \
            const float2 cax = make_float2((CR), (CR));                     \
            const float2 sax = make_float2((SR), (SR));                     \
            float2 t0, t1;                                                  \
            t0.x = cax.x * cy01.x + sax.x * sy01.x;                         \
            t0.y = cax.y * cy01.y + sax.y * sy01.y;                         \
            t1.x = cax.x * cy23.x + sax.x * sy23.x;                         \
            t1.y = cax.y * cy23.y + sax.y * sy23.y;                         \
            p0[idx].x *= t0.x; p0[idx].y *= t0.y;                           \
            p1[idx].x *= t1.x; p1[idx].y *= t1.y;                           \
        }

        QROW(0, cxa.x, sxa.x)
        QROW(1, cxa.y, sxa.y)
        QROW(2, cxa.z, sxa.z)
        QROW(3, cxa.w, sxa.w)
        QROW(4, cxb.x, sxb.x)
        QROW(5, cxb.y, sxb.y)
        QROW(6, cxb.z, sxb.z)
        QROW(7, cxb.w, sxb.w)
#undef QROW
    }

    // Store 8 rows x 4 cols as float4 (16B-aligned; col0+c0 multiple of 4).
    float* outp = out + (size_t)(row0 + r0) * m + col0 + c0;
    const size_t hstep = (size_t)64 * m;
#pragma unroll
    for (int a = 0; a < 8; ++a) {
        float4 v;
        v.x = fabsf(p0[a].x);
        v.y = fabsf(p0[a].y);
        v.z = fabsf(p1[a].x);
        v.w = fabsf(p1[a].y);
        float* dst = outp + (size_t)(a & 3) * m + ((a >> 2) ? hstep : 0);
        *(float4*)dst = v;
    }
}

extern "C" void kernel_launch(void* const* d_in, const int* in_sizes, int n_in,
                              void* d_out, int out_size, void* d_ws, size_t ws_size,
                              hipStream_t stream) {
    const float* x = (const float*)d_in[0];
    const float* y = (const float*)d_in[1];
    float* out = (float*)d_out;
    const int n = in_sizes[0] / D;  // 2048
    const int m = in_sizes[1] / D;  // 2048
    dim3 grid(n / BR, m / BC);      // 16 x 32 = 512 blocks -> 2 blocks/CU
    qkern<<<grid, NT, 0, stream>>>(x, y, out, n, m);
}